// Round 1
// baseline (219.070 us; speedup 1.0000x reference)
//
#include <hip/hip_runtime.h>
#include <math.h>

// Problem constants (from reference setup_inputs)
//   N=2, C_out=64, C_in=3, H=256, Wf=129 (=256/2+1), output irfft2 to 256x256
#define H_   256
#define Wf_  129
#define HWf_ 33024      // 256*129
#define NHW_ 66048      // 2*HWf_
#define CIN_ 3
#define COUT_ 64

// ---------------------------------------------------------------------------
// Stage 1: Xhat[n,ci,h,w] = X[ci] + (1/64) * sum_co D[ci]*(Y/a - num/den)
//   num = Y*sum|D|^2 + a*sum(conj(D)*X),  den = a*sum|D|^2 + a^2,  a=alpha/3
// Thread layout: block=256; tid&63 -> one of 64 consecutive (n,h,w) positions,
// tid>>6 -> which quarter of the 64 co values. LDS-reduce the 4 partials.
// ---------------------------------------------------------------------------
__global__ __launch_bounds__(256) void solve_stage1(
    const float2* __restrict__ X, const float2* __restrict__ D,
    const float2* __restrict__ Y, const float* __restrict__ alpha,
    float2* __restrict__ Xhat)
{
    const int tid = threadIdx.x;
    const int cog = tid >> 6;          // 0..3 (co quarter)
    const int l   = tid & 63;
    const int p   = blockIdx.x * 64 + l;   // 0..66047 over (n,h,w); 1032 blocks exact
    const int n   = p / HWf_;
    const int hw  = p - n * HWf_;

    const float a    = alpha[n] * (1.0f / 3.0f);
    const float inva = 1.0f / a;
    const float a2   = a * a;

    const float2 x0 = X[n * (CIN_ * HWf_) + 0 * HWf_ + hw];
    const float2 x1 = X[n * (CIN_ * HWf_) + 1 * HWf_ + hw];
    const float2 x2 = X[n * (CIN_ * HWf_) + 2 * HWf_ + hw];

    const float2* Dp = D + (size_t)n * (COUT_ * CIN_ * HWf_)
                         + (size_t)(cog * 16) * (CIN_ * HWf_) + hw;
    const float2* Yp = Y + (size_t)n * (COUT_ * HWf_)
                         + (size_t)(cog * 16) * HWf_ + hw;

    float ar0 = 0.f, ai0 = 0.f, ar1 = 0.f, ai1 = 0.f, ar2 = 0.f, ai2 = 0.f;

#pragma unroll 4
    for (int co = 0; co < 16; ++co) {
        float2 y  = Yp[co * HWf_];
        float2 d0 = Dp[co * (CIN_ * HWf_) + 0 * HWf_];
        float2 d1 = Dp[co * (CIN_ * HWf_) + 1 * HWf_];
        float2 d2 = Dp[co * (CIN_ * HWf_) + 2 * HWf_];

        float s2 = d0.x*d0.x + d0.y*d0.y + d1.x*d1.x + d1.y*d1.y
                 + d2.x*d2.x + d2.y*d2.y;
        // sdx = sum_ci conj(d)*x
        float sr = d0.x*x0.x + d0.y*x0.y + d1.x*x1.x + d1.y*x1.y
                 + d2.x*x2.x + d2.y*x2.y;
        float si = d0.x*x0.y - d0.y*x0.x + d1.x*x1.y - d1.y*x1.x
                 + d2.x*x2.y - d2.y*x2.x;

        float nr = y.x * s2 + a * sr;
        float ni = y.y * s2 + a * si;
        float invden = 1.0f / (a * s2 + a2);
        float cr = nr * invden, cim = ni * invden;

        float tr = y.x * inva - cr;
        float ti = y.y * inva - cim;

        ar0 += d0.x*tr - d0.y*ti;  ai0 += d0.x*ti + d0.y*tr;
        ar1 += d1.x*tr - d1.y*ti;  ai1 += d1.x*ti + d1.y*tr;
        ar2 += d2.x*tr - d2.y*ti;  ai2 += d2.x*ti + d2.y*tr;
    }

    __shared__ float red[6][256];
    red[0][tid] = ar0; red[1][tid] = ai0; red[2][tid] = ar1;
    red[3][tid] = ai1; red[4][tid] = ar2; red[5][tid] = ai2;
    __syncthreads();

    if (tid < 64) {
        float s[6];
#pragma unroll
        for (int c2 = 0; c2 < 6; ++c2)
            s[c2] = red[c2][tid] + red[c2][tid + 64]
                  + red[c2][tid + 128] + red[c2][tid + 192];
        const float inv64 = 1.0f / 64.0f;
        float2* o = Xhat + n * (CIN_ * HWf_) + hw;
        o[0]         = make_float2(x0.x + s[0] * inv64, x0.y + s[1] * inv64);
        o[HWf_]      = make_float2(x1.x + s[2] * inv64, x1.y + s[3] * inv64);
        o[2 * HWf_]  = make_float2(x2.x + s[4] * inv64, x2.y + s[5] * inv64);
    }
}

// ---------------------------------------------------------------------------
// Stage 2: complex inverse DFT along h (length 256, 1/256 normalization).
//   t[h] = (1/256) * sum_k Xhat[k] * e^{+2*pi*i*k*h/256}
// One block per (n,ci,w) column; thread = output h.
// ---------------------------------------------------------------------------
__global__ __launch_bounds__(256) void solve_stage2(
    const float2* __restrict__ in, float2* __restrict__ out)
{
    __shared__ float2 col[256];
    __shared__ float2 tw[256];

    const int b    = blockIdx.x;        // 0..773 over (n*3+ci)*129 + w
    const int n_ci = b / Wf_;           // 0..5
    const int w    = b - n_ci * Wf_;
    const int h    = threadIdx.x;

    const float2* src = in + (size_t)n_ci * HWf_ + w;
    col[h] = src[h * Wf_];

    float sv, cv;
    sincosf((float)h * (float)(2.0 * M_PI / 256.0), &sv, &cv);
    tw[h] = make_float2(cv, sv);
    __syncthreads();

    float ar = 0.f, ai = 0.f;
#pragma unroll 8
    for (int k = 0; k < 256; ++k) {
        float2 v = col[k];               // broadcast (same k across lanes)
        float2 t = tw[(k * h) & 255];
        ar += v.x * t.x - v.y * t.y;
        ai += v.x * t.y + v.y * t.x;
    }

    float2* dst = out + (size_t)n_ci * HWf_ + w;
    dst[h * Wf_] = make_float2(ar * (1.0f / 256.0f), ai * (1.0f / 256.0f));
}

// ---------------------------------------------------------------------------
// Stage 3: c2r inverse DFT along w (n=256 from 129 bins, 1/256 normalization).
// numpy/pocketfft semantics: imag of bin 0 and bin 128 (Nyquist) are ignored.
//   x[m] = (1/256)[Re X0 + (-1)^m Re X128 + 2*sum_{k=1}^{127}(Xr cos - Xi sin)]
// One block per (n,ci,h) row; thread = output sample m.
// ---------------------------------------------------------------------------
__global__ __launch_bounds__(256) void solve_stage3(
    const float2* __restrict__ in, float* __restrict__ out)
{
    __shared__ float2 row[Wf_];
    __shared__ float2 tw[256];

    const int b = blockIdx.x;           // (n*3+ci)*256 + h, 1536 blocks
    const int m = threadIdx.x;

    if (m < Wf_) row[m] = in[(size_t)b * Wf_ + m];
    float sv, cv;
    sincosf((float)m * (float)(2.0 * M_PI / 256.0), &sv, &cv);
    tw[m] = make_float2(cv, sv);
    __syncthreads();

    float acc = 0.5f * row[0].x;
    float nyq = 0.5f * row[128].x;
    acc += (m & 1) ? -nyq : nyq;

#pragma unroll 8
    for (int k = 1; k < 128; ++k) {
        float2 v = row[k];               // broadcast
        float2 t = tw[(k * m) & 255];
        acc += v.x * t.x - v.y * t.y;    // Re(X_k * e^{+i theta})
    }

    out[(size_t)b * 256 + m] = acc * (2.0f / 256.0f);
}

// ---------------------------------------------------------------------------
extern "C" void kernel_launch(void* const* d_in, const int* in_sizes, int n_in,
                              void* d_out, int out_size, void* d_ws, size_t ws_size,
                              hipStream_t stream) {
    const float2* X     = (const float2*)d_in[0];  // (2,1,3,256,129,2)
    const float2* D     = (const float2*)d_in[1];  // (2,64,3,256,129,2)
    const float2* Y     = (const float2*)d_in[2];  // (2,64,1,256,129,2)
    const float*  alpha = (const float*)d_in[3];   // (2,1,1,1)
    // d_in[4] = x_size (int64[2]) -- hardcoded 256x256

    float2* ws1 = (float2*)d_ws;            // Xhat: 6*33024 complex = 1.585 MB
    float2* ws2 = ws1 + (size_t)CIN_ * 2 * HWf_;  // h-ifft result, same size

    solve_stage1<<<NHW_ / 64, 256, 0, stream>>>(X, D, Y, alpha, ws1);
    solve_stage2<<<2 * CIN_ * Wf_, 256, 0, stream>>>(ws1, ws2);      // 774 blocks
    solve_stage3<<<2 * CIN_ * H_, 256, 0, stream>>>(ws2, (float*)d_out); // 1536 blocks
}

// Round 2
// 216.629 us; speedup vs baseline: 1.0113x; 1.0113x over previous
//
#include <hip/hip_runtime.h>
#include <math.h>

// Problem constants: N=2, C_out=64, C_in=3, H=256, Wf=129, irfft2 to 256x256
#define H_   256
#define Wf_  129
#define HWf_ 33024      // 256*129
#define CIN_ 3
#define COUT_ 64
#define TW_  0.0245436926f   // 2*pi/256

// ---------------------------------------------------------------------------
// Stage 1: Xhat[n,ci,hw] = X[ci] + (1/64) * sum_co D[ci]*(Y/a - num/den)
//   num = Y*sum|D|^2 + a*sum(conj(D)*X),  den = a*sum|D|^2 + a^2,  a=alpha/3
// Each thread: one PAIR of consecutive hw positions (float4 loads), 4 co.
// Block 256 = 16 pairs x 16 co-groups; LDS-reduce 16 partials.
// Grid 2064 blocks (8.06/CU).
// ---------------------------------------------------------------------------
__global__ __launch_bounds__(256) void solve_stage1(
    const float* __restrict__ X, const float* __restrict__ D,
    const float* __restrict__ Y, const float* __restrict__ alpha,
    float* __restrict__ Xhat)
{
    const int tid  = threadIdx.x;
    const int pl   = tid & 15;              // pair lane 0..15
    const int cog  = tid >> 4;              // co-group 0..15
    const int pair = blockIdx.x * 16 + pl;
    const int pos0 = pair * 2;              // global complex position
    const int n    = pos0 / HWf_;           // uniform per block (1032 blocks/n)
    const int hw0  = pos0 - n * HWf_;

    const float a    = alpha[n] * (1.0f / 3.0f);
    const float inva = 1.0f / a;
    const float a2   = a * a;

    float4 x[3];
#pragma unroll
    for (int ci = 0; ci < 3; ++ci)
        x[ci] = *(const float4*)(X + ((size_t)(n * 3 + ci) * HWf_ + hw0) * 2);

    const int co0 = cog * 4;
    const float* Dp = D + ((size_t)(n * 64 + co0) * 3) * (HWf_ * 2) + hw0 * 2;
    const float* Yp = Y + ((size_t)(n * 64 + co0)) * (HWf_ * 2) + hw0 * 2;

    // acc layout: q = pos*6 + ci*2 + (0=re,1=im)
    float acc[12];
#pragma unroll
    for (int q = 0; q < 12; ++q) acc[q] = 0.f;

#pragma unroll
    for (int co = 0; co < 4; ++co) {
        float4 y  = *(const float4*)(Yp + (size_t)co * (HWf_ * 2));
        float4 d0 = *(const float4*)(Dp + (size_t)(co * 3 + 0) * (HWf_ * 2));
        float4 d1 = *(const float4*)(Dp + (size_t)(co * 3 + 1) * (HWf_ * 2));
        float4 d2 = *(const float4*)(Dp + (size_t)(co * 3 + 2) * (HWf_ * 2));

        // position 0 (components .x=re,.y=im)
        {
            float s2 = d0.x*d0.x + d0.y*d0.y + d1.x*d1.x + d1.y*d1.y
                     + d2.x*d2.x + d2.y*d2.y;
            float sr = d0.x*x[0].x + d0.y*x[0].y + d1.x*x[1].x + d1.y*x[1].y
                     + d2.x*x[2].x + d2.y*x[2].y;
            float si = d0.x*x[0].y - d0.y*x[0].x + d1.x*x[1].y - d1.y*x[1].x
                     + d2.x*x[2].y - d2.y*x[2].x;
            float nr = y.x * s2 + a * sr, ni = y.y * s2 + a * si;
            float invden = 1.0f / (a * s2 + a2);
            float tr = y.x * inva - nr * invden;
            float ti = y.y * inva - ni * invden;
            acc[0] += d0.x*tr - d0.y*ti;  acc[1] += d0.x*ti + d0.y*tr;
            acc[2] += d1.x*tr - d1.y*ti;  acc[3] += d1.x*ti + d1.y*tr;
            acc[4] += d2.x*tr - d2.y*ti;  acc[5] += d2.x*ti + d2.y*tr;
        }
        // position 1 (components .z=re,.w=im)
        {
            float s2 = d0.z*d0.z + d0.w*d0.w + d1.z*d1.z + d1.w*d1.w
                     + d2.z*d2.z + d2.w*d2.w;
            float sr = d0.z*x[0].z + d0.w*x[0].w + d1.z*x[1].z + d1.w*x[1].w
                     + d2.z*x[2].z + d2.w*x[2].w;
            float si = d0.z*x[0].w - d0.w*x[0].z + d1.z*x[1].w - d1.w*x[1].z
                     + d2.z*x[2].w - d2.w*x[2].z;
            float nr = y.z * s2 + a * sr, ni = y.w * s2 + a * si;
            float invden = 1.0f / (a * s2 + a2);
            float tr = y.z * inva - nr * invden;
            float ti = y.w * inva - ni * invden;
            acc[6]  += d0.z*tr - d0.w*ti;  acc[7]  += d0.z*ti + d0.w*tr;
            acc[8]  += d1.z*tr - d1.w*ti;  acc[9]  += d1.z*ti + d1.w*tr;
            acc[10] += d2.z*tr - d2.w*ti;  acc[11] += d2.z*ti + d2.w*tr;
        }
    }

    __shared__ float red[16 * 192];   // [cog][pair][q] = 12 KB
    {
        const int base = cog * 192 + pl * 12;
#pragma unroll
        for (int q = 0; q < 12; ++q) red[base + q] = acc[q];
    }
    __syncthreads();

    if (tid < 192) {
        float s = 0.f;
#pragma unroll
        for (int c = 0; c < 16; ++c) s += red[c * 192 + tid];
        const int P   = tid / 12;
        const int r   = tid - P * 12;
        const int pos = r / 6;
        const int rr  = r - pos * 6;
        const int ci  = rr >> 1;
        const int cc  = rr & 1;
        const int gp  = (blockIdx.x * 16 + P) * 2 + pos;
        const int hw  = gp - n * HWf_;
        const size_t o = ((size_t)(n * 3 + ci) * HWf_ + hw) * 2 + cc;
        Xhat[o] = X[o] + s * (1.0f / 64.0f);
    }
}

// ---------------------------------------------------------------------------
// Stage 2: inverse complex DFT along h (length 256, 1/256 norm).
//   out[h] = (1/256) sum_k in[k] e^{+i 2pi k h/256}
// Block = 128 threads, one column (n_ci,w); thread t computes h=t and h=t+128
// (twiddle differs by (-1)^k). Twiddle via register recurrence, exact refresh
// every 32 steps from integer-reduced argument.
// ---------------------------------------------------------------------------
__global__ __launch_bounds__(128) void solve_stage2(
    const float2* __restrict__ in, float2* __restrict__ out)
{
    __shared__ float2 col[256];

    const int b    = blockIdx.x;        // n_ci*129 + w, 774 blocks
    const int n_ci = b / Wf_;
    const int w    = b - n_ci * Wf_;
    const int t    = threadIdx.x;       // 0..127

    const float2* src = in + (size_t)n_ci * HWf_ + w;
    col[t]       = src[t * Wf_];
    col[t + 128] = src[(t + 128) * Wf_];
    __syncthreads();

    float wc, wsn;
    sincosf((float)t * TW_, &wsn, &wc);   // step multiplier e^{i*2pi*t/256}

    float ar = 0.f, ai = 0.f, br = 0.f, bi = 0.f;
    for (int kb = 0; kb < 8; ++kb) {
        const int k0 = kb * 32;
        float tr, ti;
        {
            const int m = (t * k0) & 255;     // exact integer phase reduction
            float s, c; sincosf((float)m * TW_, &s, &c);
            tr = c; ti = s;
        }
#pragma unroll
        for (int j = 0; j < 32; ++j) {
            const float2 v = col[k0 + j];     // broadcast, conflict-free
            const float pr = v.x * tr - v.y * ti;
            const float pi = v.x * ti + v.y * tr;
            ar += pr; ai += pi;
            if ((k0 + j) & 1) { br -= pr; bi -= pi; }
            else             { br += pr; bi += pi; }
            const float nt = tr * wc - ti * wsn;
            ti = tr * wsn + ti * wc;
            tr = nt;
        }
    }

    float2* dst = out + (size_t)n_ci * HWf_ + w;
    dst[t * Wf_]         = make_float2(ar * (1.0f / 256.0f), ai * (1.0f / 256.0f));
    dst[(t + 128) * Wf_] = make_float2(br * (1.0f / 256.0f), bi * (1.0f / 256.0f));
}

// ---------------------------------------------------------------------------
// Stage 3: c2r inverse DFT along w (n=256 from 129 bins, 1/256 norm),
// numpy semantics (imag of bins 0 and 128 ignored):
//   x[m] = (1/256)[X0.re + (-1)^m X128.re + 2 sum_{k=1}^{127}(Xr cos - Xi sin)]
// Block = 128 threads, one row; thread t computes m=t and m=t+128.
// Loop includes k=0 fully, then subtracts the overcount.
// ---------------------------------------------------------------------------
__global__ __launch_bounds__(128) void solve_stage3(
    const float2* __restrict__ in, float* __restrict__ out)
{
    __shared__ float2 row[Wf_];

    const int b = blockIdx.x;           // (n*3+ci)*256 + h, 1536 blocks
    const int t = threadIdx.x;          // 0..127

    row[t] = in[(size_t)b * Wf_ + t];
    if (t == 0) row[128] = in[(size_t)b * Wf_ + 128];
    __syncthreads();

    float wc, wsn;
    sincosf((float)t * TW_, &wsn, &wc);

    float sa = 0.f, sb = 0.f;           // sums over k=0..127 for m=t, m=t+128
    for (int kb = 0; kb < 4; ++kb) {
        const int k0 = kb * 32;
        float tr, ti;
        {
            const int m = (t * k0) & 255;
            float s, c; sincosf((float)m * TW_, &s, &c);
            tr = c; ti = s;
        }
#pragma unroll
        for (int j = 0; j < 32; ++j) {
            const float2 v = row[k0 + j];     // broadcast
            const float pr = v.x * tr - v.y * ti;   // Re(X_k e^{+i th})
            sa += pr;
            if ((k0 + j) & 1) sb -= pr; else sb += pr;
            const float nt = tr * wc - ti * wsn;
            ti = tr * wsn + ti * wc;
            tr = nt;
        }
    }

    const float sgn  = (t & 1) ? -1.0f : 1.0f;     // (-1)^m, same for m and m+128
    const float base = -0.5f * row[0].x + sgn * 0.5f * row[128].x;
    out[(size_t)b * 256 + t]       = (sa + base) * (1.0f / 128.0f);
    out[(size_t)b * 256 + t + 128] = (sb + base) * (1.0f / 128.0f);
}

// ---------------------------------------------------------------------------
extern "C" void kernel_launch(void* const* d_in, const int* in_sizes, int n_in,
                              void* d_out, int out_size, void* d_ws, size_t ws_size,
                              hipStream_t stream) {
    const float* X     = (const float*)d_in[0];  // (2,1,3,256,129,2)
    const float* D     = (const float*)d_in[1];  // (2,64,3,256,129,2)
    const float* Y     = (const float*)d_in[2];  // (2,64,1,256,129,2)
    const float* alpha = (const float*)d_in[3];  // (2,)
    // d_in[4] = x_size (int64[2]) -- hardcoded 256x256

    float* ws1 = (float*)d_ws;                       // Xhat: 6*33024 cplx
    float2* ws2 = (float2*)(ws1 + (size_t)CIN_ * 2 * HWf_ * 2);

    solve_stage1<<<2064, 256, 0, stream>>>(X, D, Y, alpha, ws1);
    solve_stage2<<<2 * CIN_ * Wf_, 128, 0, stream>>>((const float2*)ws1, ws2);
    solve_stage3<<<2 * CIN_ * H_, 128, 0, stream>>>(ws2, (float*)d_out);
}

// Round 4
// 204.162 us; speedup vs baseline: 1.0730x; 1.0611x over previous
//
#include <hip/hip_runtime.h>
#include <math.h>

// Problem constants: N=2, C_out=64, C_in=3, H=256, Wf=129, irfft2 to 256x256
#define H_   256
#define Wf_  129
#define HWf_ 33024      // 256*129
#define CIN_ 3
#define COUT_ 64
#define TW_  0.0245436926f   // 2*pi/256

typedef float f32x4 __attribute__((ext_vector_type(4)));  // builtin-compatible

// ---------------------------------------------------------------------------
// Stage 1: Xhat[n,ci,hw] = X[ci] + (1/64) * sum_co D[ci]*(Y/a - num/den)
//   num = Y*sum|D|^2 + a*sum(conj(D)*X),  den = a*sum|D|^2 + a^2,  a=alpha/3
// Each thread: one PAIR of consecutive hw positions (16B loads), 4 co.
// Block 256 = 16 pairs x 16 co-groups; LDS-reduce 16 partials.
// Grid 2064 blocks (8.06/CU). D/Y are zero-reuse -> nontemporal loads.
// ---------------------------------------------------------------------------
__global__ __launch_bounds__(256) void solve_stage1(
    const float* __restrict__ X, const float* __restrict__ D,
    const float* __restrict__ Y, const float* __restrict__ alpha,
    float* __restrict__ Xhat)
{
    const int tid  = threadIdx.x;
    const int pl   = tid & 15;              // pair lane 0..15
    const int cog  = tid >> 4;              // co-group 0..15
    const int pair = blockIdx.x * 16 + pl;
    const int pos0 = pair * 2;              // global complex position
    const int n    = pos0 / HWf_;           // uniform per block (1032 blocks/n)
    const int hw0  = pos0 - n * HWf_;

    const float a    = alpha[n] * (1.0f / 3.0f);
    const float inva = 1.0f / a;
    const float a2   = a * a;

    f32x4 x[3];
#pragma unroll
    for (int ci = 0; ci < 3; ++ci)
        x[ci] = *(const f32x4*)(X + ((size_t)(n * 3 + ci) * HWf_ + hw0) * 2);

    const int co0 = cog * 4;
    const float* Dp = D + ((size_t)(n * 64 + co0) * 3) * (HWf_ * 2) + hw0 * 2;
    const float* Yp = Y + ((size_t)(n * 64 + co0)) * (HWf_ * 2) + hw0 * 2;

    // acc layout: q = pos*6 + ci*2 + (0=re,1=im)
    float acc[12];
#pragma unroll
    for (int q = 0; q < 12; ++q) acc[q] = 0.f;

#pragma unroll
    for (int co = 0; co < 4; ++co) {
        f32x4 y  = __builtin_nontemporal_load(
                       (const f32x4*)(Yp + (size_t)co * (HWf_ * 2)));
        f32x4 d0 = __builtin_nontemporal_load(
                       (const f32x4*)(Dp + (size_t)(co * 3 + 0) * (HWf_ * 2)));
        f32x4 d1 = __builtin_nontemporal_load(
                       (const f32x4*)(Dp + (size_t)(co * 3 + 1) * (HWf_ * 2)));
        f32x4 d2 = __builtin_nontemporal_load(
                       (const f32x4*)(Dp + (size_t)(co * 3 + 2) * (HWf_ * 2)));

        // position 0 (components 0=re,1=im)
        {
            float s2 = d0[0]*d0[0] + d0[1]*d0[1] + d1[0]*d1[0] + d1[1]*d1[1]
                     + d2[0]*d2[0] + d2[1]*d2[1];
            float sr = d0[0]*x[0][0] + d0[1]*x[0][1] + d1[0]*x[1][0] + d1[1]*x[1][1]
                     + d2[0]*x[2][0] + d2[1]*x[2][1];
            float si = d0[0]*x[0][1] - d0[1]*x[0][0] + d1[0]*x[1][1] - d1[1]*x[1][0]
                     + d2[0]*x[2][1] - d2[1]*x[2][0];
            float nr = y[0] * s2 + a * sr, ni = y[1] * s2 + a * si;
            float invden = 1.0f / (a * s2 + a2);
            float tr = y[0] * inva - nr * invden;
            float ti = y[1] * inva - ni * invden;
            acc[0] += d0[0]*tr - d0[1]*ti;  acc[1] += d0[0]*ti + d0[1]*tr;
            acc[2] += d1[0]*tr - d1[1]*ti;  acc[3] += d1[0]*ti + d1[1]*tr;
            acc[4] += d2[0]*tr - d2[1]*ti;  acc[5] += d2[0]*ti + d2[1]*tr;
        }
        // position 1 (components 2=re,3=im)
        {
            float s2 = d0[2]*d0[2] + d0[3]*d0[3] + d1[2]*d1[2] + d1[3]*d1[3]
                     + d2[2]*d2[2] + d2[3]*d2[3];
            float sr = d0[2]*x[0][2] + d0[3]*x[0][3] + d1[2]*x[1][2] + d1[3]*x[1][3]
                     + d2[2]*x[2][2] + d2[3]*x[2][3];
            float si = d0[2]*x[0][3] - d0[3]*x[0][2] + d1[2]*x[1][3] - d1[3]*x[1][2]
                     + d2[2]*x[2][3] - d2[3]*x[2][2];
            float nr = y[2] * s2 + a * sr, ni = y[3] * s2 + a * si;
            float invden = 1.0f / (a * s2 + a2);
            float tr = y[2] * inva - nr * invden;
            float ti = y[3] * inva - ni * invden;
            acc[6]  += d0[2]*tr - d0[3]*ti;  acc[7]  += d0[2]*ti + d0[3]*tr;
            acc[8]  += d1[2]*tr - d1[3]*ti;  acc[9]  += d1[2]*ti + d1[3]*tr;
            acc[10] += d2[2]*tr - d2[3]*ti;  acc[11] += d2[2]*ti + d2[3]*tr;
        }
    }

    __shared__ float red[16 * 192];   // [cog][pair][q] = 12 KB
    {
        const int base = cog * 192 + pl * 12;
#pragma unroll
        for (int q = 0; q < 12; ++q) red[base + q] = acc[q];
    }
    __syncthreads();

    if (tid < 192) {
        float s = 0.f;
#pragma unroll
        for (int c = 0; c < 16; ++c) s += red[c * 192 + tid];
        const int P   = tid / 12;
        const int r   = tid - P * 12;
        const int pos = r / 6;
        const int rr  = r - pos * 6;
        const int ci  = rr >> 1;
        const int cc  = rr & 1;
        const int gp  = (blockIdx.x * 16 + P) * 2 + pos;
        const int hw  = gp - n * HWf_;
        const size_t o = ((size_t)(n * 3 + ci) * HWf_ + hw) * 2 + cc;
        Xhat[o] = X[o] + s * (1.0f / 64.0f);
    }
}

// ---------------------------------------------------------------------------
// Stage 2: inverse complex DFT along h (length 256, 1/256 norm).
//   out[h] = (1/256) sum_k in[k] e^{+i 2pi k h/256}
// Block = 128 threads, one column (n_ci,w); thread t computes h=t and h=t+128
// (twiddle differs by (-1)^k). Twiddle via register recurrence, exact refresh
// every 32 steps from integer-reduced argument.
// ---------------------------------------------------------------------------
__global__ __launch_bounds__(128) void solve_stage2(
    const float2* __restrict__ in, float2* __restrict__ out)
{
    __shared__ float2 col[256];

    const int b    = blockIdx.x;        // n_ci*129 + w, 774 blocks
    const int n_ci = b / Wf_;
    const int w    = b - n_ci * Wf_;
    const int t    = threadIdx.x;       // 0..127

    const float2* src = in + (size_t)n_ci * HWf_ + w;
    col[t]       = src[t * Wf_];
    col[t + 128] = src[(t + 128) * Wf_];
    __syncthreads();

    float wc, wsn;
    sincosf((float)t * TW_, &wsn, &wc);   // step multiplier e^{i*2pi*t/256}

    float ar = 0.f, ai = 0.f, br = 0.f, bi = 0.f;
    for (int kb = 0; kb < 8; ++kb) {
        const int k0 = kb * 32;
        float tr, ti;
        {
            const int m = (t * k0) & 255;     // exact integer phase reduction
            float s, c; sincosf((float)m * TW_, &s, &c);
            tr = c; ti = s;
        }
#pragma unroll
        for (int j = 0; j < 32; ++j) {
            const float2 v = col[k0 + j];     // broadcast, conflict-free
            const float pr = v.x * tr - v.y * ti;
            const float pi = v.x * ti + v.y * tr;
            ar += pr; ai += pi;
            if ((k0 + j) & 1) { br -= pr; bi -= pi; }
            else             { br += pr; bi += pi; }
            const float nt = tr * wc - ti * wsn;
            ti = tr * wsn + ti * wc;
            tr = nt;
        }
    }

    float2* dst = out + (size_t)n_ci * HWf_ + w;
    dst[t * Wf_]         = make_float2(ar * (1.0f / 256.0f), ai * (1.0f / 256.0f));
    dst[(t + 128) * Wf_] = make_float2(br * (1.0f / 256.0f), bi * (1.0f / 256.0f));
}

// ---------------------------------------------------------------------------
// Stage 3: c2r inverse DFT along w (n=256 from 129 bins, 1/256 norm),
// numpy semantics (imag of bins 0 and 128 ignored):
//   x[m] = (1/256)[X0.re + (-1)^m X128.re + 2 sum_{k=1}^{127}(Xr cos - Xi sin)]
// Block = 128 threads, one row; thread t computes m=t and m=t+128.
// ---------------------------------------------------------------------------
__global__ __launch_bounds__(128) void solve_stage3(
    const float2* __restrict__ in, float* __restrict__ out)
{
    __shared__ float2 row[Wf_];

    const int b = blockIdx.x;           // (n*3+ci)*256 + h, 1536 blocks
    const int t = threadIdx.x;          // 0..127

    row[t] = in[(size_t)b * Wf_ + t];
    if (t == 0) row[128] = in[(size_t)b * Wf_ + 128];
    __syncthreads();

    float wc, wsn;
    sincosf((float)t * TW_, &wsn, &wc);

    float sa = 0.f, sb = 0.f;           // sums over k=0..127 for m=t, m=t+128
    for (int kb = 0; kb < 4; ++kb) {
        const int k0 = kb * 32;
        float tr, ti;
        {
            const int m = (t * k0) & 255;
            float s, c; sincosf((float)m * TW_, &s, &c);
            tr = c; ti = s;
        }
#pragma unroll
        for (int j = 0; j < 32; ++j) {
            const float2 v = row[k0 + j];     // broadcast
            const float pr = v.x * tr - v.y * ti;   // Re(X_k e^{+i th})
            sa += pr;
            if ((k0 + j) & 1) sb -= pr; else sb += pr;
            const float nt = tr * wc - ti * wsn;
            ti = tr * wsn + ti * wc;
            tr = nt;
        }
    }

    const float sgn  = (t & 1) ? -1.0f : 1.0f;     // (-1)^m, same for m and m+128
    const float base = -0.5f * row[0].x + sgn * 0.5f * row[128].x;
    out[(size_t)b * 256 + t]       = (sa + base) * (1.0f / 128.0f);
    out[(size_t)b * 256 + t + 128] = (sb + base) * (1.0f / 128.0f);
}

// ---------------------------------------------------------------------------
extern "C" void kernel_launch(void* const* d_in, const int* in_sizes, int n_in,
                              void* d_out, int out_size, void* d_ws, size_t ws_size,
                              hipStream_t stream) {
    const float* X     = (const float*)d_in[0];  // (2,1,3,256,129,2)
    const float* D     = (const float*)d_in[1];  // (2,64,3,256,129,2)
    const float* Y     = (const float*)d_in[2];  // (2,64,1,256,129,2)
    const float* alpha = (const float*)d_in[3];  // (2,)
    // d_in[4] = x_size (int64[2]) -- hardcoded 256x256

    float* ws1 = (float*)d_ws;                       // Xhat: 6*33024 cplx
    float2* ws2 = (float2*)(ws1 + (size_t)CIN_ * 2 * HWf_ * 2);

    solve_stage1<<<2064, 256, 0, stream>>>(X, D, Y, alpha, ws1);
    solve_stage2<<<2 * CIN_ * Wf_, 128, 0, stream>>>((const float2*)ws1, ws2);
    solve_stage3<<<2 * CIN_ * H_, 128, 0, stream>>>(ws2, (float*)d_out);
}